// Round 13
// baseline (419.585 us; speedup 1.0000x reference)
//
#include <hip/hip_runtime.h>
#include <hip/hip_bf16.h>
#include <hip/hip_fp16.h>

#define NNODES 100000
#define NEDGES 1600000
#define NGRAPH 64
#define NCOPY  32           // spread copies for BN-stat atomics
#define NSLOT  8            // LDS pool graph slots per block

// fill partitioning (plain stores only — NOT for atomics; r9 lesson)
#define NPART   8
#define PSIZE   (NNODES / NPART)      // 12500
#define ECH     2047
#define NSLICE  782                   // 782*2047 >= E
#define NPB     (NSLICE * NPART)      // 6256
#define NGEMM1  1563                  // ceil(N/64)
#define NB      391                   // ceil(N/256) scan blocks

// ---------------------------------------------------------------- fused degree(int4) + GEMM1 (x@W1 -> fp16, unscaled)
__global__ __launch_bounds__(256) void k_deg_gemm1(const float* __restrict__ A,
                                                   const float* __restrict__ W,
                                                   __half* __restrict__ hd,
                                                   const int* __restrict__ ei,
                                                   unsigned* __restrict__ indeg) {
    const int b = blockIdx.x;
    const int tid = threadIdx.x;

    if (b & 1) {
        int base = (b >> 1) * 1024 + tid * 4;
        if (base < NEDGES) {
            int4 d = *reinterpret_cast<const int4*>(&ei[NEDGES + base]);
            atomicAdd(&indeg[d.x], 1u);
            atomicAdd(&indeg[d.y], 1u);
            atomicAdd(&indeg[d.z], 1u);
            atomicAdd(&indeg[d.w], 1u);
        }
        return;
    }

    __shared__ float wlds[64 * 64];
    __shared__ float alds[64 * 68];
    const int row0 = (b >> 1) * 64;
    const int tc = (tid & 15) * 4;
    const int tr = (tid >> 4) * 4;
    float acc[4][4];
    #pragma unroll
    for (int i = 0; i < 4; ++i)
        #pragma unroll
        for (int j = 0; j < 4; ++j) acc[i][j] = 0.f;

    for (int kc = 0; kc < 2; ++kc) {
        for (int idx = tid; idx < 64 * 16; idx += 256) {
            int r = idx >> 4, kk = (idx & 15) * 4;
            *reinterpret_cast<float4*>(&wlds[r * 64 + kk]) =
                *reinterpret_cast<const float4*>(&W[(kc * 64 + r) * 64 + kk]);
        }
        for (int idx = tid; idx < 64 * 16; idx += 256) {
            int r = idx >> 4, kk = (idx & 15) * 4;
            int row = row0 + r;
            float4 v = make_float4(0.f, 0.f, 0.f, 0.f);
            if (row < NNODES) v = *reinterpret_cast<const float4*>(&A[row * 128 + kc * 64 + kk]);
            *reinterpret_cast<float4*>(&alds[r * 68 + kk]) = v;
        }
        __syncthreads();
        #pragma unroll 8
        for (int k = 0; k < 64; ++k) {
            float4 wv = *reinterpret_cast<const float4*>(&wlds[k * 64 + tc]);
            float av[4];
            #pragma unroll
            for (int i = 0; i < 4; ++i) av[i] = alds[(tr + i) * 68 + k];
            #pragma unroll
            for (int i = 0; i < 4; ++i) {
                acc[i][0] = fmaf(av[i], wv.x, acc[i][0]);
                acc[i][1] = fmaf(av[i], wv.y, acc[i][1]);
                acc[i][2] = fmaf(av[i], wv.z, acc[i][2]);
                acc[i][3] = fmaf(av[i], wv.w, acc[i][3]);
            }
        }
        __syncthreads();
    }
    #pragma unroll
    for (int i = 0; i < 4; ++i) {
        int row = row0 + tr + i;
        if (row < NNODES) {
            __half2* p = reinterpret_cast<__half2*>(&hd[(size_t)row * 64 + tc]);
            p[0] = __floats2half2_rn(acc[i][0], acc[i][1]);
            p[1] = __floats2half2_rn(acc[i][2], acc[i][3]);
        }
    }
}

// ---------------------------------------------------------------- single-kernel scan (decoupled lookback)
// publish[b] = 0x80000000 | blocksum, all 391 blocks resident -> spin is safe.
__global__ __launch_bounds__(256) void k_scan(const unsigned* __restrict__ indeg,
                                              unsigned* __restrict__ publish,
                                              unsigned* __restrict__ rowptr,
                                              unsigned* __restrict__ cursor,
                                              float* __restrict__ dinv, int n) {
    __shared__ unsigned s[256];
    __shared__ unsigned offs[256];
    const int tid = threadIdx.x;
    const int b = blockIdx.x;
    int i = b * 256 + tid;
    unsigned v = (i < n) ? indeg[i] : 0u;
    s[tid] = v;
    __syncthreads();
    for (int off = 1; off < 256; off <<= 1) {
        unsigned u = (tid >= off) ? s[tid - off] : 0u;
        __syncthreads();
        s[tid] += u;
        __syncthreads();
    }
    if (tid == 0) atomicExch(&publish[b], 0x80000000u | s[255]);
    // lookback over blocks [0, b)
    unsigned p = 0;
    for (int j = tid; j < b; j += 256) {
        unsigned val;
        do { val = atomicAdd(&publish[j], 0u); } while (!(val & 0x80000000u));
        p += val & 0x7fffffffu;
    }
    offs[tid] = p;
    __syncthreads();
    for (int off = 128; off > 0; off >>= 1) {
        if (tid < off) offs[tid] += offs[tid + off];
        __syncthreads();
    }
    unsigned boff = offs[0];
    if (i < n) {
        unsigned ex = s[tid] - v + boff;
        rowptr[i] = ex;
        cursor[i] = ex;
        dinv[i]   = rsqrtf((float)(v + 1u));
        if (i == n - 1) rowptr[n] = s[tid] + boff;
    }
}

// ---------------------------------------------------------------- XCD-partitioned CSR fill
__global__ __launch_bounds__(256) void k_fill(const int* __restrict__ ei,
                                              unsigned* __restrict__ cursor,
                                              unsigned* __restrict__ colidx) {
    const int p   = blockIdx.x & (NPART - 1);
    const int plo = p * PSIZE;
    const int phi = plo + PSIZE;
    const int s   = blockIdx.x >> 3;
    const int e0  = s * ECH;
    const int e1  = min(e0 + ECH, NEDGES);
    for (int e = e0 + threadIdx.x; e < e1; e += 256) {
        int dst = ei[NEDGES + e];
        if (dst >= plo && dst < phi) {
            int src = ei[e];
            unsigned pos = atomicAdd(&cursor[dst], 1u);
            colidx[pos] = (unsigned)src;
        }
    }
}

// ---------------------------------------------------------------- fp16 row accumulate (4 ch / lane, 8 B loads)
__device__ __forceinline__ void acc_row(const __half* __restrict__ hd, unsigned s, int c0, float4& acc) {
    uint2 u = *reinterpret_cast<const uint2*>(&hd[(size_t)s * 64 + c0]);
    __half2 x01 = *reinterpret_cast<__half2*>(&u.x);
    __half2 x23 = *reinterpret_cast<__half2*>(&u.y);
    float2 f01 = __half22float2(x01);
    float2 f23 = __half22float2(x23);
    acc.x += f01.x; acc.y += f01.y; acc.z += f23.x; acc.w += f23.y;
}
__device__ __forceinline__ void acc_row_s(const __half* __restrict__ hd, const float* __restrict__ dinv,
                                          unsigned s, int c0, float4& acc) {
    float ds = dinv[s];
    uint2 u = *reinterpret_cast<const uint2*>(&hd[(size_t)s * 64 + c0]);
    __half2 x01 = *reinterpret_cast<__half2*>(&u.x);
    __half2 x23 = *reinterpret_cast<__half2*>(&u.y);
    float2 f01 = __half22float2(x01);
    float2 f23 = __half22float2(x23);
    acc.x = fmaf(f01.x, ds, acc.x); acc.y = fmaf(f01.y, ds, acc.y);
    acc.z = fmaf(f23.x, ds, acc.z); acc.w = fmaf(f23.y, ds, acc.w);
}

#define WAVE_REDUCE_8(s0,s1,s2,s3,q0,q1,q2,q3)                      \
    {                                                                \
        _Pragma("unroll")                                            \
        for (int m = 16; m < 64; m <<= 1) {                          \
            s0 += __shfl_xor(s0, m); s1 += __shfl_xor(s1, m);        \
            s2 += __shfl_xor(s2, m); s3 += __shfl_xor(s3, m);        \
            q0 += __shfl_xor(q0, m); q1 += __shfl_xor(q1, m);        \
            q2 += __shfl_xor(q2, m); q3 += __shfl_xor(q3, m);        \
        }                                                            \
    }

// ---------------------------------------------------------------- gather1 + BN stats + LAST-BLOCK BN1 fold -> W2eff, c2
__global__ __launch_bounds__(256) void k_gather_fused(const unsigned* __restrict__ rowptr,
                                                      const unsigned* __restrict__ colidx,
                                                      const __half* __restrict__ hd,
                                                      const float* __restrict__ dinv,
                                                      const float* __restrict__ bias,
                                                      __half* __restrict__ act16,
                                                      float* bn_sum, float* bn_sq,
                                                      const float* __restrict__ W2,
                                                      const float* __restrict__ gamma,
                                                      const float* __restrict__ beta,
                                                      float* __restrict__ W2eff,
                                                      float* __restrict__ c2,
                                                      unsigned* ticket, int n) {
    const int tid = threadIdx.x;
    const int grp = tid >> 4;
    const int c0  = (tid & 15) * 4;
    float4 bv = *reinterpret_cast<const float4*>(&bias[c0]);
    float s0=0.f,s1=0.f,s2=0.f,s3=0.f, q0=0.f,q1=0.f,q2=0.f,q3=0.f;

    #pragma unroll
    for (int it = 0; it < 2; ++it) {
        int node = blockIdx.x * 32 + grp * 2 + it;
        if (node < n) {
            unsigned lo = rowptr[node], hi = rowptr[node + 1];
            float4 acc = make_float4(0.f, 0.f, 0.f, 0.f);
            acc_row_s(hd, dinv, (unsigned)node, c0, acc);
            unsigned j = lo;
            for (; j + 4 <= hi; j += 4) {
                unsigned a0 = colidx[j], a1 = colidx[j+1], a2 = colidx[j+2], a3 = colidx[j+3];
                acc_row_s(hd, dinv, a0, c0, acc);
                acc_row_s(hd, dinv, a1, c0, acc);
                acc_row_s(hd, dinv, a2, c0, acc);
                acc_row_s(hd, dinv, a3, c0, acc);
            }
            for (; j < hi; ++j) acc_row_s(hd, dinv, colidx[j], c0, acc);
            float w = dinv[node];
            float4 r;
            r.x = fmaxf(fmaf(acc.x, w, bv.x), 0.f);
            r.y = fmaxf(fmaf(acc.y, w, bv.y), 0.f);
            r.z = fmaxf(fmaf(acc.z, w, bv.z), 0.f);
            r.w = fmaxf(fmaf(acc.w, w, bv.w), 0.f);
            __half2 h01 = __floats2half2_rn(r.x, r.y);
            __half2 h23 = __floats2half2_rn(r.z, r.w);
            uint2 u;
            u.x = *reinterpret_cast<unsigned*>(&h01);
            u.y = *reinterpret_cast<unsigned*>(&h23);
            *reinterpret_cast<uint2*>(&act16[(size_t)node * 64 + c0]) = u;
            s0 += r.x; s1 += r.y; s2 += r.z; s3 += r.w;
            q0 = fmaf(r.x, r.x, q0); q1 = fmaf(r.y, r.y, q1);
            q2 = fmaf(r.z, r.z, q2); q3 = fmaf(r.w, r.w, q3);
        }
    }

    WAVE_REDUCE_8(s0,s1,s2,s3,q0,q1,q2,q3);
    __shared__ float ls[4 * 64];
    __shared__ float lq[4 * 64];
    int lane = tid & 63, wid = tid >> 6;
    if (lane < 16) {
        *reinterpret_cast<float4*>(&ls[wid * 64 + lane * 4]) = make_float4(s0, s1, s2, s3);
        *reinterpret_cast<float4*>(&lq[wid * 64 + lane * 4]) = make_float4(q0, q1, q2, q3);
    }
    __syncthreads();
    if (tid < 64) {
        int cpy = (blockIdx.x & (NCOPY - 1)) * 64;
        float S = ls[tid] + ls[64 + tid] + ls[128 + tid] + ls[192 + tid];
        float Q = lq[tid] + lq[64 + tid] + lq[128 + tid] + lq[192 + tid];
        atomicAdd(&bn_sum[cpy + tid], S);
        atomicAdd(&bn_sq[cpy + tid],  Q);
    }

    // ---- last-block BN1 fold (syncthreads drains this block's atomics before the ticket)
    __syncthreads();
    __shared__ unsigned rank_s;
    if (tid == 0) rank_s = atomicAdd(ticket, 1u);
    __syncthreads();
    if (rank_s == gridDim.x - 1) {
        __shared__ float sc[64], sh[64];
        if (tid < 64) {
            float S = 0.f, Q = 0.f;
            #pragma unroll
            for (int cpy = 0; cpy < NCOPY; ++cpy) {
                S += atomicAdd(&bn_sum[cpy * 64 + tid], 0.f);   // atomic read: cross-XCD safe
                Q += atomicAdd(&bn_sq[cpy * 64 + tid],  0.f);
            }
            float inv_n = 1.0f / (float)n;
            float mu  = S * inv_n;
            float var = Q * inv_n - mu * mu;
            float sv = gamma[tid] * rsqrtf(var + 1e-5f);
            sc[tid] = sv; sh[tid] = beta[tid] - mu * sv;
        }
        __syncthreads();
        if (tid < 64) {
            float acc = 0.f;
            for (int k = 0; k < 64; ++k) {
                float w = W2[k * 64 + tid];
                W2eff[k * 64 + tid] = sc[k] * w;
                acc = fmaf(sh[k], w, acc);
            }
            c2[tid] = acc;
        }
    }
}

// ---------------------------------------------------------------- gather2 + pool + BN2 stats
__global__ __launch_bounds__(256) void k_gather_pool(const unsigned* __restrict__ rowptr,
                                                     const unsigned* __restrict__ colidx,
                                                     const __half* __restrict__ hd,
                                                     const float* __restrict__ dinv,
                                                     const float* __restrict__ bias,
                                                     const int* __restrict__ batch,
                                                     float* __restrict__ gsum,
                                                     float* bn_sum, float* bn_sq, int n) {
    const int tid = threadIdx.x;
    const int grp = tid >> 4;
    const int c0  = (tid & 15) * 4;
    float4 bv = *reinterpret_cast<const float4*>(&bias[c0]);
    float s0=0.f,s1=0.f,s2=0.f,s3=0.f, q0=0.f,q1=0.f,q2=0.f,q3=0.f;

    __shared__ float lds_pool[NSLOT * 64];
    for (int i = tid; i < NSLOT * 64; i += 256) lds_pool[i] = 0.f;
    int node0 = blockIdx.x * 32;
    int g0 = batch[node0 < n ? node0 : (n - 1)];
    __syncthreads();

    #pragma unroll
    for (int it = 0; it < 2; ++it) {
        int node = node0 + grp * 2 + it;
        if (node < n) {
            unsigned lo = rowptr[node], hi = rowptr[node + 1];
            float4 acc = make_float4(0.f, 0.f, 0.f, 0.f);
            acc_row(hd, (unsigned)node, c0, acc);
            unsigned j = lo;
            for (; j + 4 <= hi; j += 4) {
                unsigned a0 = colidx[j], a1 = colidx[j+1], a2 = colidx[j+2], a3 = colidx[j+3];
                acc_row(hd, a0, c0, acc);
                acc_row(hd, a1, c0, acc);
                acc_row(hd, a2, c0, acc);
                acc_row(hd, a3, c0, acc);
            }
            for (; j < hi; ++j) acc_row(hd, colidx[j], c0, acc);
            float w = dinv[node];
            float4 r;
            r.x = fmaxf(fmaf(acc.x, w, bv.x), 0.f);
            r.y = fmaxf(fmaf(acc.y, w, bv.y), 0.f);
            r.z = fmaxf(fmaf(acc.z, w, bv.z), 0.f);
            r.w = fmaxf(fmaf(acc.w, w, bv.w), 0.f);
            s0 += r.x; s1 += r.y; s2 += r.z; s3 += r.w;
            q0 = fmaf(r.x, r.x, q0); q1 = fmaf(r.y, r.y, q1);
            q2 = fmaf(r.z, r.z, q2); q3 = fmaf(r.w, r.w, q3);
            int slot = batch[node] - g0;
            if (slot < NSLOT) {
                atomicAdd(&lds_pool[slot * 64 + c0 + 0], r.x);
                atomicAdd(&lds_pool[slot * 64 + c0 + 1], r.y);
                atomicAdd(&lds_pool[slot * 64 + c0 + 2], r.z);
                atomicAdd(&lds_pool[slot * 64 + c0 + 3], r.w);
            } else {
                int g = g0 + slot;
                atomicAdd(&gsum[g * 64 + c0 + 0], r.x);
                atomicAdd(&gsum[g * 64 + c0 + 1], r.y);
                atomicAdd(&gsum[g * 64 + c0 + 2], r.z);
                atomicAdd(&gsum[g * 64 + c0 + 3], r.w);
            }
        }
    }

    WAVE_REDUCE_8(s0,s1,s2,s3,q0,q1,q2,q3);
    __shared__ float ls[4 * 64];
    __shared__ float lq[4 * 64];
    int lane = tid & 63, wid = tid >> 6;
    if (lane < 16) {
        *reinterpret_cast<float4*>(&ls[wid * 64 + lane * 4]) = make_float4(s0, s1, s2, s3);
        *reinterpret_cast<float4*>(&lq[wid * 64 + lane * 4]) = make_float4(q0, q1, q2, q3);
    }
    __syncthreads();
    if (tid < 64) {
        int cpy = (blockIdx.x & (NCOPY - 1)) * 64;
        float S = ls[tid] + ls[64 + tid] + ls[128 + tid] + ls[192 + tid];
        float Q = lq[tid] + lq[64 + tid] + lq[128 + tid] + lq[192 + tid];
        atomicAdd(&bn_sum[cpy + tid], S);
        atomicAdd(&bn_sq[cpy + tid],  Q);
        #pragma unroll
        for (int sl = 0; sl < NSLOT; ++sl) {
            int g = g0 + sl;
            if (g < NGRAPH) {
                float v = lds_pool[sl * 64 + tid];
                if (v != 0.f) atomicAdd(&gsum[g * 64 + tid], v);
            }
        }
    }
}

// ---------------------------------------------------------------- GEMM2: act16 @ W2eff + c2, *dinv -> fp16
__global__ __launch_bounds__(256) void k_gemm64_h(const __half* __restrict__ A16,
                                                  const float* __restrict__ W,
                                                  const float* __restrict__ addvec,
                                                  const float* __restrict__ rowscale,
                                                  __half* __restrict__ hd, int n) {
    __shared__ float wlds[64 * 64];
    __shared__ float alds[64 * 68];
    const int tid = threadIdx.x;
    const int tc  = (tid & 15) * 4;
    const int tr  = (tid >> 4) * 4;
    const int row0 = blockIdx.x * 64;

    float acc[4][4];
    float4 cv = *reinterpret_cast<const float4*>(&addvec[tc]);
    #pragma unroll
    for (int i = 0; i < 4; ++i) { acc[i][0]=cv.x; acc[i][1]=cv.y; acc[i][2]=cv.z; acc[i][3]=cv.w; }

    {
        for (int idx = tid; idx < 64 * 16; idx += 256) {
            int r = idx >> 4, kk = (idx & 15) * 4;
            *reinterpret_cast<float4*>(&wlds[r * 64 + kk]) =
                *reinterpret_cast<const float4*>(&W[r * 64 + kk]);
        }
        for (int idx = tid; idx < 64 * 16; idx += 256) {
            int r = idx >> 4, kk = (idx & 15) * 4;
            int row = row0 + r;
            float4 v = make_float4(0.f, 0.f, 0.f, 0.f);
            if (row < n) {
                uint2 u = *reinterpret_cast<const uint2*>(&A16[(size_t)row * 64 + kk]);
                __half2 x01 = *reinterpret_cast<__half2*>(&u.x);
                __half2 x23 = *reinterpret_cast<__half2*>(&u.y);
                float2 f01 = __half22float2(x01);
                float2 f23 = __half22float2(x23);
                v = make_float4(f01.x, f01.y, f23.x, f23.y);
            }
            *reinterpret_cast<float4*>(&alds[r * 68 + kk]) = v;
        }
        __syncthreads();
        #pragma unroll 8
        for (int k = 0; k < 64; ++k) {
            float4 wv = *reinterpret_cast<const float4*>(&wlds[k * 64 + tc]);
            float av[4];
            #pragma unroll
            for (int i = 0; i < 4; ++i) av[i] = alds[(tr + i) * 68 + k];
            #pragma unroll
            for (int i = 0; i < 4; ++i) {
                acc[i][0] = fmaf(av[i], wv.x, acc[i][0]);
                acc[i][1] = fmaf(av[i], wv.y, acc[i][1]);
                acc[i][2] = fmaf(av[i], wv.z, acc[i][2]);
                acc[i][3] = fmaf(av[i], wv.w, acc[i][3]);
            }
        }
    }
    #pragma unroll
    for (int i = 0; i < 4; ++i) {
        int row = row0 + tr + i;
        if (row < n) {
            float f = rowscale[row];
            __half2* p = reinterpret_cast<__half2*>(&hd[(size_t)row * 64 + tc]);
            p[0] = __floats2half2_rn(acc[i][0] * f, acc[i][1] * f);
            p[1] = __floats2half2_rn(acc[i][2] * f, acc[i][3] * f);
        }
    }
}

// ---------------------------------------------------------------- MLP head (+ BN2 finalize + pool finalize)
__device__ __forceinline__ int lower_bound_i(const int* a, int n, int v) {
    int lo = 0, hi = n;
    while (lo < hi) { int m = (lo + hi) >> 1; if (a[m] < v) lo = m + 1; else hi = m; }
    return lo;
}
__global__ __launch_bounds__(128) void k_mlp(const float* __restrict__ gsum,
                                             const int* __restrict__ batch, int n,
                                             const float* __restrict__ bn_sum, const float* __restrict__ bn_sq,
                                             const float* __restrict__ gamma, const float* __restrict__ beta,
                                             const float* __restrict__ fW1, const float* __restrict__ fb1,
                                             const float* __restrict__ fW2, const float* __restrict__ fb2,
                                             const float* __restrict__ fW3, const float* __restrict__ fb3,
                                             const float* __restrict__ fW4, const float* __restrict__ fb4,
                                             const float* __restrict__ oW,  const float* __restrict__ ob,
                                             float* __restrict__ out) {
    int g = blockIdx.x;
    int t = threadIdx.x;
    __shared__ float a[128], bbuf[128];
    if (t < 64) {
        float S = 0.f, Q = 0.f;
        #pragma unroll
        for (int cpy = 0; cpy < NCOPY; ++cpy) { S += bn_sum[cpy * 64 + t]; Q += bn_sq[cpy * 64 + t]; }
        float inv_n = 1.0f / (float)n;
        float mu  = S * inv_n;
        float var = Q * inv_n - mu * mu;
        float s   = gamma[t] * rsqrtf(var + 1e-5f);
        float sh  = beta[t] - mu * s;
        int lo = lower_bound_i(batch, n, g);
        int hi = lower_bound_i(batch, n, g + 1);
        int cnt = hi - lo;
        a[t] = (cnt > 0) ? (gsum[g * 64 + t] / (float)cnt) * s + sh : 0.f;
    }
    __syncthreads();
    {
        float acc = fb1[t];
        for (int k = 0; k < 64; ++k) acc = fmaf(a[k], fW1[k * 128 + t], acc);
        bbuf[t] = fmaxf(acc, 0.f);
    }
    __syncthreads();
    if (t < 64) {
        float acc = fb2[t];
        for (int k = 0; k < 128; ++k) acc = fmaf(bbuf[k], fW2[k * 64 + t], acc);
        a[t] = fmaxf(acc, 0.f);
    }
    __syncthreads();
    if (t < 32) {
        float acc = fb3[t];
        for (int k = 0; k < 64; ++k) acc = fmaf(a[k], fW3[k * 32 + t], acc);
        bbuf[t] = fmaxf(acc, 0.f);
    }
    __syncthreads();
    if (t < 16) {
        float acc = fb4[t];
        for (int k = 0; k < 32; ++k) acc = fmaf(bbuf[k], fW4[k * 16 + t], acc);
        a[t] = fmaxf(acc, 0.f);
    }
    __syncthreads();
    if (t == 0) {
        float acc = ob[0];
        for (int k = 0; k < 16; ++k) acc = fmaf(a[k], oW[k], acc);
        out[g] = acc;
    }
}

// ---------------------------------------------------------------- launch
extern "C" void kernel_launch(void* const* d_in, const int* in_sizes, int n_in,
                              void* d_out, int out_size, void* d_ws, size_t ws_size,
                              hipStream_t stream) {
    const float* x      = (const float*)d_in[0];
    const int*   ei     = (const int*)  d_in[1];
    const int*   batch  = (const int*)  d_in[2];
    const float* W1     = (const float*)d_in[3];
    const float* b1     = (const float*)d_in[4];
    const float* W2     = (const float*)d_in[5];
    const float* b2     = (const float*)d_in[6];
    const float* gamma1 = (const float*)d_in[7];
    const float* beta1  = (const float*)d_in[8];
    const float* gamma2 = (const float*)d_in[9];
    const float* beta2  = (const float*)d_in[10];
    const float* fW1    = (const float*)d_in[11];
    const float* fb1    = (const float*)d_in[12];
    const float* fW2    = (const float*)d_in[13];
    const float* fb2    = (const float*)d_in[14];
    const float* fW3    = (const float*)d_in[15];
    const float* fb3    = (const float*)d_in[16];
    const float* fW4    = (const float*)d_in[17];
    const float* fb4    = (const float*)d_in[18];
    const float* oW     = (const float*)d_in[19];
    const float* ob     = (const float*)d_in[20];
    float* out = (float*)d_out;

    const int N = NNODES, E = NEDGES, G = NGRAPH;

    // workspace layout (byte-based)
    char* base = (char*)d_ws;
    __half*   hd     = (__half*)base;                                  // N*64 fp16
    __half*   act16  = (__half*)(base + (size_t)N * 64 * 2);           // N*64 fp16
    unsigned* indeg  = (unsigned*)((char*)act16 + (size_t)N * 64 * 2); // N
    float*    dinv   = (float*)(indeg + N);                            // N
    unsigned* rowptr = (unsigned*)(dinv + N);                          // N+1
    unsigned* cursor = rowptr + (N + 1);                               // N
    unsigned* colidx = cursor + N;                                     // E
    float*    bn1s   = (float*)(colidx + E);                           // NCOPY*64
    float*    bn1q   = bn1s + NCOPY * 64;                              // NCOPY*64
    float*    bn2s   = bn1q + NCOPY * 64;                              // NCOPY*64
    float*    bn2q   = bn2s + NCOPY * 64;                              // NCOPY*64
    float*    gsum   = bn2q + NCOPY * 64;                              // G*64
    unsigned* publish= (unsigned*)(gsum + (size_t)G * 64);             // NB
    unsigned* ticket = publish + NB;                                   // 1
    float*    W2eff  = (float*)(ticket + 1);                           // 4096
    float*    c2     = W2eff + 4096;                                   // 64

    // --- zero accumulators (bn stats + gsum + publish + ticket contiguous) ---
    hipMemsetAsync(indeg, 0, (size_t)N * 4, stream);
    hipMemsetAsync(bn1s, 0, (size_t)(4 * NCOPY * 64 + G * 64 + NB + 1) * 4, stream);

    // --- fused degree count (int4) + GEMM1 ---
    k_deg_gemm1<<<2 * NGEMM1, 256, 0, stream>>>(x, W1, hd, ei, indeg);

    // --- single-kernel CSR scan (decoupled lookback) ---
    k_scan<<<NB, 256, 0, stream>>>(indeg, publish, rowptr, cursor, dinv, N);

    // --- XCD-partitioned fill ---
    k_fill<<<NPB, 256, 0, stream>>>(ei, cursor, colidx);

    // --- layer 1 aggregate + BN1 stats + last-block BN1 fold ---
    k_gather_fused<<<(N + 31) / 32, 256, 0, stream>>>(rowptr, colidx, hd, dinv, b1, act16,
                                                      bn1s, bn1q, W2, gamma1, beta1,
                                                      W2eff, c2, ticket, N);

    // --- layer 2: hd2 = (act16 @ W2eff + c2)*dinv, fp16 ---
    k_gemm64_h<<<(N + 63) / 64, 256, 0, stream>>>(act16, W2eff, c2, dinv, hd, N);
    k_gather_pool<<<(N + 31) / 32, 256, 0, stream>>>(rowptr, colidx, hd, dinv, b2, batch, gsum, bn2s, bn2q, N);

    // --- MLP (BN2 + pool finalize fused) ---
    k_mlp<<<G, 128, 0, stream>>>(gsum, batch, N, bn2s, bn2q, gamma2, beta2,
                                 fW1, fb1, fW2, fb2, fW3, fb3, fW4, fb4, oW, ob, out);
}

// Round 14
// 395.270 us; speedup vs baseline: 1.0615x; 1.0615x over previous
//
#include <hip/hip_runtime.h>
#include <hip/hip_bf16.h>
#include <hip/hip_fp16.h>

#define NNODES 100000
#define NEDGES 1600000
#define NGRAPH 64
#define NCOPY  32           // spread copies for BN-stat atomics
#define NSLOT  8            // LDS pool graph slots per block

// fill partitioning: 8 dst-partitions (XCD heuristic b&7), edge slices b>>3
#define NPART   8
#define PSIZE   (NNODES / NPART)      // 12500
#define ECH     2047
#define NSLICE  782                   // 782*2047 >= E
#define NFILL   (NSLICE * NPART)      // 6256
#define NGEMM1  1563                  // ceil(N/64)

// ---------------------------------------------------------------- fused degree(int4) + GEMM1 (x@W1 -> fp16, unscaled)
// odd blocks: degree count; even blocks: GEMM1 tiles
__global__ __launch_bounds__(256) void k_deg_gemm1(const float* __restrict__ A,
                                                   const float* __restrict__ W,
                                                   __half* __restrict__ hd,
                                                   const int* __restrict__ ei,
                                                   unsigned* __restrict__ indeg) {
    const int b = blockIdx.x;
    const int tid = threadIdx.x;

    if (b & 1) {
        int base = (b >> 1) * 1024 + tid * 4;
        if (base < NEDGES) {
            int4 d = *reinterpret_cast<const int4*>(&ei[NEDGES + base]);
            atomicAdd(&indeg[d.x], 1u);
            atomicAdd(&indeg[d.y], 1u);
            atomicAdd(&indeg[d.z], 1u);
            atomicAdd(&indeg[d.w], 1u);
        }
        return;
    }

    __shared__ float wlds[64 * 64];
    __shared__ float alds[64 * 68];
    const int row0 = (b >> 1) * 64;
    const int tc = (tid & 15) * 4;
    const int tr = (tid >> 4) * 4;
    float acc[4][4];
    #pragma unroll
    for (int i = 0; i < 4; ++i)
        #pragma unroll
        for (int j = 0; j < 4; ++j) acc[i][j] = 0.f;

    for (int kc = 0; kc < 2; ++kc) {
        for (int idx = tid; idx < 64 * 16; idx += 256) {
            int r = idx >> 4, kk = (idx & 15) * 4;
            *reinterpret_cast<float4*>(&wlds[r * 64 + kk]) =
                *reinterpret_cast<const float4*>(&W[(kc * 64 + r) * 64 + kk]);
        }
        for (int idx = tid; idx < 64 * 16; idx += 256) {
            int r = idx >> 4, kk = (idx & 15) * 4;
            int row = row0 + r;
            float4 v = make_float4(0.f, 0.f, 0.f, 0.f);
            if (row < NNODES) v = *reinterpret_cast<const float4*>(&A[row * 128 + kc * 64 + kk]);
            *reinterpret_cast<float4*>(&alds[r * 68 + kk]) = v;
        }
        __syncthreads();
        #pragma unroll 8
        for (int k = 0; k < 64; ++k) {
            float4 wv = *reinterpret_cast<const float4*>(&wlds[k * 64 + tc]);
            float av[4];
            #pragma unroll
            for (int i = 0; i < 4; ++i) av[i] = alds[(tr + i) * 68 + k];
            #pragma unroll
            for (int i = 0; i < 4; ++i) {
                acc[i][0] = fmaf(av[i], wv.x, acc[i][0]);
                acc[i][1] = fmaf(av[i], wv.y, acc[i][1]);
                acc[i][2] = fmaf(av[i], wv.z, acc[i][2]);
                acc[i][3] = fmaf(av[i], wv.w, acc[i][3]);
            }
        }
        __syncthreads();
    }
    #pragma unroll
    for (int i = 0; i < 4; ++i) {
        int row = row0 + tr + i;
        if (row < NNODES) {
            __half2* p = reinterpret_cast<__half2*>(&hd[(size_t)row * 64 + tc]);
            p[0] = __floats2half2_rn(acc[i][0], acc[i][1]);
            p[1] = __floats2half2_rn(acc[i][2], acc[i][3]);
        }
    }
}

// ---------------------------------------------------------------- CSR scan
__global__ __launch_bounds__(256) void k_block_reduce(const unsigned* __restrict__ v, unsigned* bsum, int n) {
    __shared__ unsigned s[256];
    int i = blockIdx.x * 256 + threadIdx.x;
    s[threadIdx.x] = (i < n) ? v[i] : 0u;
    __syncthreads();
    for (int off = 128; off > 0; off >>= 1) {
        if (threadIdx.x < off) s[threadIdx.x] += s[threadIdx.x + off];
        __syncthreads();
    }
    if (threadIdx.x == 0) bsum[blockIdx.x] = s[0];
}
__global__ __launch_bounds__(256) void k_scan_final(const unsigned* __restrict__ indeg,
                                                    const unsigned* __restrict__ bsum,
                                                    unsigned* __restrict__ rowptr,
                                                    unsigned* __restrict__ cursor,
                                                    float* __restrict__ dinv, int n) {
    __shared__ unsigned pre[256];
    __shared__ unsigned s[256];
    const int tid = threadIdx.x;
    unsigned p = 0;
    for (int i = tid; i < (int)blockIdx.x; i += 256) p += bsum[i];
    pre[tid] = p;
    __syncthreads();
    for (int off = 128; off > 0; off >>= 1) {
        if (tid < off) pre[tid] += pre[tid + off];
        __syncthreads();
    }
    unsigned boff = pre[0];
    __syncthreads();

    int i = blockIdx.x * 256 + tid;
    unsigned v = (i < n) ? indeg[i] : 0u;
    s[tid] = v;
    __syncthreads();
    for (int off = 1; off < 256; off <<= 1) {
        unsigned u = (tid >= off) ? s[tid - off] : 0u;
        __syncthreads();
        s[tid] += u;
        __syncthreads();
    }
    if (i < n) {
        unsigned ex = s[tid] - v + boff;
        rowptr[i] = ex;
        cursor[i] = ex;
        dinv[i]   = rsqrtf((float)(v + 1u));
        if (i == n - 1) rowptr[n] = s[tid] + boff;
    }
}

// ---------------------------------------------------------------- XCD-partitioned CSR fill
__global__ __launch_bounds__(256) void k_fill(const int* __restrict__ ei,
                                              unsigned* __restrict__ cursor,
                                              unsigned* __restrict__ colidx) {
    const int p   = blockIdx.x & (NPART - 1);
    const int plo = p * PSIZE;
    const int phi = plo + PSIZE;
    const int s   = blockIdx.x >> 3;
    const int e0  = s * ECH;
    const int e1  = min(e0 + ECH, NEDGES);
    for (int e = e0 + threadIdx.x; e < e1; e += 256) {
        int dst = ei[NEDGES + e];
        if (dst >= plo && dst < phi) {
            int src = ei[e];
            unsigned pos = atomicAdd(&cursor[dst], 1u);
            colidx[pos] = (unsigned)src;
        }
    }
}

// ---------------------------------------------------------------- fp16 row accumulate (4 ch / lane, 8 B loads)
__device__ __forceinline__ void acc_row(const __half* __restrict__ hd, unsigned s, int c0, float4& acc) {
    uint2 u = *reinterpret_cast<const uint2*>(&hd[(size_t)s * 64 + c0]);
    __half2 x01 = *reinterpret_cast<__half2*>(&u.x);
    __half2 x23 = *reinterpret_cast<__half2*>(&u.y);
    float2 f01 = __half22float2(x01);
    float2 f23 = __half22float2(x23);
    acc.x += f01.x; acc.y += f01.y; acc.z += f23.x; acc.w += f23.y;
}
__device__ __forceinline__ void acc_row_s(const __half* __restrict__ hd, const float* __restrict__ dinv,
                                          unsigned s, int c0, float4& acc) {
    float ds = dinv[s];
    uint2 u = *reinterpret_cast<const uint2*>(&hd[(size_t)s * 64 + c0]);
    __half2 x01 = *reinterpret_cast<__half2*>(&u.x);
    __half2 x23 = *reinterpret_cast<__half2*>(&u.y);
    float2 f01 = __half22float2(x01);
    float2 f23 = __half22float2(x23);
    acc.x = fmaf(f01.x, ds, acc.x); acc.y = fmaf(f01.y, ds, acc.y);
    acc.z = fmaf(f23.x, ds, acc.z); acc.w = fmaf(f23.y, ds, acc.w);
}

// wave-level stat reduce (16-lane channel groups)
#define WAVE_REDUCE_8(s0,s1,s2,s3,q0,q1,q2,q3)                      \
    {                                                                \
        _Pragma("unroll")                                            \
        for (int m = 16; m < 64; m <<= 1) {                          \
            s0 += __shfl_xor(s0, m); s1 += __shfl_xor(s1, m);        \
            s2 += __shfl_xor(s2, m); s3 += __shfl_xor(s3, m);        \
            q0 += __shfl_xor(q0, m); q1 += __shfl_xor(q1, m);        \
            q2 += __shfl_xor(q2, m); q3 += __shfl_xor(q3, m);        \
        }                                                            \
    }

// ---------------------------------------------------------------- gather1: hd unscaled -> scale each neighbor by dinv[src]
__global__ __launch_bounds__(256) void k_gather_fused(const unsigned* __restrict__ rowptr,
                                                      const unsigned* __restrict__ colidx,
                                                      const __half* __restrict__ hd,
                                                      const float* __restrict__ dinv,
                                                      const float* __restrict__ bias,
                                                      float* __restrict__ act,
                                                      float* bn_sum, float* bn_sq, int n) {
    const int tid = threadIdx.x;
    const int grp = tid >> 4;
    const int c0  = (tid & 15) * 4;
    float4 bv = *reinterpret_cast<const float4*>(&bias[c0]);
    float s0=0.f,s1=0.f,s2=0.f,s3=0.f, q0=0.f,q1=0.f,q2=0.f,q3=0.f;

    #pragma unroll
    for (int it = 0; it < 2; ++it) {
        int node = blockIdx.x * 32 + grp * 2 + it;
        if (node < n) {
            unsigned lo = rowptr[node], hi = rowptr[node + 1];
            float4 acc = make_float4(0.f, 0.f, 0.f, 0.f);
            acc_row_s(hd, dinv, (unsigned)node, c0, acc);
            unsigned j = lo;
            for (; j + 4 <= hi; j += 4) {
                unsigned a0 = colidx[j], a1 = colidx[j+1], a2 = colidx[j+2], a3 = colidx[j+3];
                acc_row_s(hd, dinv, a0, c0, acc);
                acc_row_s(hd, dinv, a1, c0, acc);
                acc_row_s(hd, dinv, a2, c0, acc);
                acc_row_s(hd, dinv, a3, c0, acc);
            }
            for (; j < hi; ++j) acc_row_s(hd, dinv, colidx[j], c0, acc);
            float w = dinv[node];
            float4 r;
            r.x = fmaxf(fmaf(acc.x, w, bv.x), 0.f);
            r.y = fmaxf(fmaf(acc.y, w, bv.y), 0.f);
            r.z = fmaxf(fmaf(acc.z, w, bv.z), 0.f);
            r.w = fmaxf(fmaf(acc.w, w, bv.w), 0.f);
            *reinterpret_cast<float4*>(&act[(size_t)node * 64 + c0]) = r;
            s0 += r.x; s1 += r.y; s2 += r.z; s3 += r.w;
            q0 = fmaf(r.x, r.x, q0); q1 = fmaf(r.y, r.y, q1);
            q2 = fmaf(r.z, r.z, q2); q3 = fmaf(r.w, r.w, q3);
        }
    }

    WAVE_REDUCE_8(s0,s1,s2,s3,q0,q1,q2,q3);
    __shared__ float ls[4 * 64];
    __shared__ float lq[4 * 64];
    int lane = tid & 63, wid = tid >> 6;
    if (lane < 16) {
        *reinterpret_cast<float4*>(&ls[wid * 64 + lane * 4]) = make_float4(s0, s1, s2, s3);
        *reinterpret_cast<float4*>(&lq[wid * 64 + lane * 4]) = make_float4(q0, q1, q2, q3);
    }
    __syncthreads();
    if (tid < 64) {
        int cpy = (blockIdx.x & (NCOPY - 1)) * 64;
        float S = ls[tid] + ls[64 + tid] + ls[128 + tid] + ls[192 + tid];
        float Q = lq[tid] + lq[64 + tid] + lq[128 + tid] + lq[192 + tid];
        atomicAdd(&bn_sum[cpy + tid], S);
        atomicAdd(&bn_sq[cpy + tid],  Q);
    }
}

// ---------------------------------------------------------------- gather2 + pool + BN2 stats (hd pre-scaled by dinv)
__global__ __launch_bounds__(256) void k_gather_pool(const unsigned* __restrict__ rowptr,
                                                     const unsigned* __restrict__ colidx,
                                                     const __half* __restrict__ hd,
                                                     const float* __restrict__ dinv,
                                                     const float* __restrict__ bias,
                                                     const int* __restrict__ batch,
                                                     float* __restrict__ gsum,
                                                     float* bn_sum, float* bn_sq, int n) {
    const int tid = threadIdx.x;
    const int grp = tid >> 4;
    const int c0  = (tid & 15) * 4;
    float4 bv = *reinterpret_cast<const float4*>(&bias[c0]);
    float s0=0.f,s1=0.f,s2=0.f,s3=0.f, q0=0.f,q1=0.f,q2=0.f,q3=0.f;

    __shared__ float lds_pool[NSLOT * 64];
    for (int i = tid; i < NSLOT * 64; i += 256) lds_pool[i] = 0.f;
    int node0 = blockIdx.x * 32;
    int g0 = batch[node0 < n ? node0 : (n - 1)];
    __syncthreads();

    #pragma unroll
    for (int it = 0; it < 2; ++it) {
        int node = node0 + grp * 2 + it;
        if (node < n) {
            unsigned lo = rowptr[node], hi = rowptr[node + 1];
            float4 acc = make_float4(0.f, 0.f, 0.f, 0.f);
            acc_row(hd, (unsigned)node, c0, acc);
            unsigned j = lo;
            for (; j + 4 <= hi; j += 4) {
                unsigned a0 = colidx[j], a1 = colidx[j+1], a2 = colidx[j+2], a3 = colidx[j+3];
                acc_row(hd, a0, c0, acc);
                acc_row(hd, a1, c0, acc);
                acc_row(hd, a2, c0, acc);
                acc_row(hd, a3, c0, acc);
            }
            for (; j < hi; ++j) acc_row(hd, colidx[j], c0, acc);
            float w = dinv[node];
            float4 r;
            r.x = fmaxf(fmaf(acc.x, w, bv.x), 0.f);
            r.y = fmaxf(fmaf(acc.y, w, bv.y), 0.f);
            r.z = fmaxf(fmaf(acc.z, w, bv.z), 0.f);
            r.w = fmaxf(fmaf(acc.w, w, bv.w), 0.f);
            s0 += r.x; s1 += r.y; s2 += r.z; s3 += r.w;
            q0 = fmaf(r.x, r.x, q0); q1 = fmaf(r.y, r.y, q1);
            q2 = fmaf(r.z, r.z, q2); q3 = fmaf(r.w, r.w, q3);
            int slot = batch[node] - g0;
            if (slot < NSLOT) {
                atomicAdd(&lds_pool[slot * 64 + c0 + 0], r.x);
                atomicAdd(&lds_pool[slot * 64 + c0 + 1], r.y);
                atomicAdd(&lds_pool[slot * 64 + c0 + 2], r.z);
                atomicAdd(&lds_pool[slot * 64 + c0 + 3], r.w);
            } else {
                int g = g0 + slot;
                atomicAdd(&gsum[g * 64 + c0 + 0], r.x);
                atomicAdd(&gsum[g * 64 + c0 + 1], r.y);
                atomicAdd(&gsum[g * 64 + c0 + 2], r.z);
                atomicAdd(&gsum[g * 64 + c0 + 3], r.w);
            }
        }
    }

    WAVE_REDUCE_8(s0,s1,s2,s3,q0,q1,q2,q3);
    __shared__ float ls[4 * 64];
    __shared__ float lq[4 * 64];
    int lane = tid & 63, wid = tid >> 6;
    if (lane < 16) {
        *reinterpret_cast<float4*>(&ls[wid * 64 + lane * 4]) = make_float4(s0, s1, s2, s3);
        *reinterpret_cast<float4*>(&lq[wid * 64 + lane * 4]) = make_float4(q0, q1, q2, q3);
    }
    __syncthreads();
    if (tid < 64) {
        int cpy = (blockIdx.x & (NCOPY - 1)) * 64;
        float S = ls[tid] + ls[64 + tid] + ls[128 + tid] + ls[192 + tid];
        float Q = lq[tid] + lq[64 + tid] + lq[128 + tid] + lq[192 + tid];
        atomicAdd(&bn_sum[cpy + tid], S);
        atomicAdd(&bn_sq[cpy + tid],  Q);
        #pragma unroll
        for (int sl = 0; sl < NSLOT; ++sl) {
            int g = g0 + sl;
            if (g < NGRAPH) {
                float v = lds_pool[sl * 64 + tid];
                if (v != 0.f) atomicAdd(&gsum[g * 64 + tid], v);
            }
        }
    }
}

// ---------------------------------------------------------------- BN1 folded into W2 (sums spread copies)
__global__ void k_bn_fold_w2(const float* __restrict__ bn_sum, const float* __restrict__ bn_sq,
                             const float* __restrict__ gamma, const float* __restrict__ beta,
                             const float* __restrict__ W2, float* __restrict__ W2eff,
                             float* __restrict__ c2, int n) {
    __shared__ float sc[64], sh[64];
    int t = threadIdx.x;
    float S = 0.f, Q = 0.f;
    #pragma unroll
    for (int cpy = 0; cpy < NCOPY; ++cpy) { S += bn_sum[cpy * 64 + t]; Q += bn_sq[cpy * 64 + t]; }
    float inv_n = 1.0f / (float)n;
    float mu  = S * inv_n;
    float var = Q * inv_n - mu * mu;
    float s = gamma[t] * rsqrtf(var + 1e-5f);
    sc[t] = s; sh[t] = beta[t] - mu * s;
    __syncthreads();
    float acc = 0.f;
    for (int k = 0; k < 64; ++k) {
        float w = W2[k * 64 + t];
        W2eff[k * 64 + t] = sc[k] * w;
        acc = fmaf(sh[k], w, acc);
    }
    c2[t] = acc;
}

// ---------------------------------------------------------------- GEMM2: act @ W2eff + c2, *dinv -> fp16
__global__ __launch_bounds__(256) void k_gemm64_h(const float* __restrict__ A,
                                                  const float* __restrict__ W,
                                                  const float* __restrict__ addvec,
                                                  const float* __restrict__ rowscale,
                                                  __half* __restrict__ hd, int n) {
    __shared__ float wlds[64 * 64];
    __shared__ float alds[64 * 68];
    const int tid = threadIdx.x;
    const int tc  = (tid & 15) * 4;
    const int tr  = (tid >> 4) * 4;
    const int row0 = blockIdx.x * 64;

    float acc[4][4];
    float4 cv = *reinterpret_cast<const float4*>(&addvec[tc]);
    #pragma unroll
    for (int i = 0; i < 4; ++i) { acc[i][0]=cv.x; acc[i][1]=cv.y; acc[i][2]=cv.z; acc[i][3]=cv.w; }

    {
        for (int idx = tid; idx < 64 * 16; idx += 256) {
            int r = idx >> 4, kk = (idx & 15) * 4;
            *reinterpret_cast<float4*>(&wlds[r * 64 + kk]) =
                *reinterpret_cast<const float4*>(&W[r * 64 + kk]);
        }
        for (int idx = tid; idx < 64 * 16; idx += 256) {
            int r = idx >> 4, kk = (idx & 15) * 4;
            int row = row0 + r;
            float4 v = make_float4(0.f, 0.f, 0.f, 0.f);
            if (row < n) v = *reinterpret_cast<const float4*>(&A[row * 64 + kk]);
            *reinterpret_cast<float4*>(&alds[r * 68 + kk]) = v;
        }
        __syncthreads();
        #pragma unroll 8
        for (int k = 0; k < 64; ++k) {
            float4 wv = *reinterpret_cast<const float4*>(&wlds[k * 64 + tc]);
            float av[4];
            #pragma unroll
            for (int i = 0; i < 4; ++i) av[i] = alds[(tr + i) * 68 + k];
            #pragma unroll
            for (int i = 0; i < 4; ++i) {
                acc[i][0] = fmaf(av[i], wv.x, acc[i][0]);
                acc[i][1] = fmaf(av[i], wv.y, acc[i][1]);
                acc[i][2] = fmaf(av[i], wv.z, acc[i][2]);
                acc[i][3] = fmaf(av[i], wv.w, acc[i][3]);
            }
        }
    }
    #pragma unroll
    for (int i = 0; i < 4; ++i) {
        int row = row0 + tr + i;
        if (row < n) {
            float f = rowscale[row];
            __half2* p = reinterpret_cast<__half2*>(&hd[(size_t)row * 64 + tc]);
            p[0] = __floats2half2_rn(acc[i][0] * f, acc[i][1] * f);
            p[1] = __floats2half2_rn(acc[i][2] * f, acc[i][3] * f);
        }
    }
}

// ---------------------------------------------------------------- MLP head (+ BN2 finalize + pool finalize)
__device__ __forceinline__ int lower_bound_i(const int* a, int n, int v) {
    int lo = 0, hi = n;
    while (lo < hi) { int m = (lo + hi) >> 1; if (a[m] < v) lo = m + 1; else hi = m; }
    return lo;
}
__global__ __launch_bounds__(128) void k_mlp(const float* __restrict__ gsum,
                                             const int* __restrict__ batch, int n,
                                             const float* __restrict__ bn_sum, const float* __restrict__ bn_sq,
                                             const float* __restrict__ gamma, const float* __restrict__ beta,
                                             const float* __restrict__ fW1, const float* __restrict__ fb1,
                                             const float* __restrict__ fW2, const float* __restrict__ fb2,
                                             const float* __restrict__ fW3, const float* __restrict__ fb3,
                                             const float* __restrict__ fW4, const float* __restrict__ fb4,
                                             const float* __restrict__ oW,  const float* __restrict__ ob,
                                             float* __restrict__ out) {
    int g = blockIdx.x;
    int t = threadIdx.x;
    __shared__ float a[128], bbuf[128];
    if (t < 64) {
        float S = 0.f, Q = 0.f;
        #pragma unroll
        for (int cpy = 0; cpy < NCOPY; ++cpy) { S += bn_sum[cpy * 64 + t]; Q += bn_sq[cpy * 64 + t]; }
        float inv_n = 1.0f / (float)n;
        float mu  = S * inv_n;
        float var = Q * inv_n - mu * mu;
        float s   = gamma[t] * rsqrtf(var + 1e-5f);
        float sh  = beta[t] - mu * s;
        int lo = lower_bound_i(batch, n, g);
        int hi = lower_bound_i(batch, n, g + 1);
        int cnt = hi - lo;
        a[t] = (cnt > 0) ? (gsum[g * 64 + t] / (float)cnt) * s + sh : 0.f;
    }
    __syncthreads();
    {
        float acc = fb1[t];
        for (int k = 0; k < 64; ++k) acc = fmaf(a[k], fW1[k * 128 + t], acc);
        bbuf[t] = fmaxf(acc, 0.f);
    }
    __syncthreads();
    if (t < 64) {
        float acc = fb2[t];
        for (int k = 0; k < 128; ++k) acc = fmaf(bbuf[k], fW2[k * 64 + t], acc);
        a[t] = fmaxf(acc, 0.f);
    }
    __syncthreads();
    if (t < 32) {
        float acc = fb3[t];
        for (int k = 0; k < 64; ++k) acc = fmaf(a[k], fW3[k * 32 + t], acc);
        bbuf[t] = fmaxf(acc, 0.f);
    }
    __syncthreads();
    if (t < 16) {
        float acc = fb4[t];
        for (int k = 0; k < 32; ++k) acc = fmaf(bbuf[k], fW4[k * 16 + t], acc);
        a[t] = fmaxf(acc, 0.f);
    }
    __syncthreads();
    if (t == 0) {
        float acc = ob[0];
        for (int k = 0; k < 16; ++k) acc = fmaf(a[k], oW[k], acc);
        out[g] = acc;
    }
}

// ---------------------------------------------------------------- launch
extern "C" void kernel_launch(void* const* d_in, const int* in_sizes, int n_in,
                              void* d_out, int out_size, void* d_ws, size_t ws_size,
                              hipStream_t stream) {
    const float* x      = (const float*)d_in[0];
    const int*   ei     = (const int*)  d_in[1];
    const int*   batch  = (const int*)  d_in[2];
    const float* W1     = (const float*)d_in[3];
    const float* b1     = (const float*)d_in[4];
    const float* W2     = (const float*)d_in[5];
    const float* b2     = (const float*)d_in[6];
    const float* gamma1 = (const float*)d_in[7];
    const float* beta1  = (const float*)d_in[8];
    const float* gamma2 = (const float*)d_in[9];
    const float* beta2  = (const float*)d_in[10];
    const float* fW1    = (const float*)d_in[11];
    const float* fb1    = (const float*)d_in[12];
    const float* fW2    = (const float*)d_in[13];
    const float* fb2    = (const float*)d_in[14];
    const float* fW3    = (const float*)d_in[15];
    const float* fb3    = (const float*)d_in[16];
    const float* fW4    = (const float*)d_in[17];
    const float* fb4    = (const float*)d_in[18];
    const float* oW     = (const float*)d_in[19];
    const float* ob     = (const float*)d_in[20];
    float* out = (float*)d_out;

    const int N = NNODES, E = NEDGES, G = NGRAPH;
    const int NB = (N + 255) / 256;   // 391

    // workspace layout (byte-based)
    char* base = (char*)d_ws;
    __half*   hd     = (__half*)base;                                  // N*64 fp16
    float*    act    = (float*)(base + (size_t)N * 64 * 2);            // N*64 fp32
    unsigned* indeg  = (unsigned*)((char*)act + (size_t)N * 64 * 4);   // N
    float*    dinv   = (float*)(indeg + N);                            // N
    unsigned* rowptr = (unsigned*)(dinv + N);                          // N+1
    unsigned* cursor = rowptr + (N + 1);                               // N
    unsigned* colidx = cursor + N;                                     // E
    unsigned* bsum   = colidx + E;                                     // 512
    float*    bn1s   = (float*)(bsum + 512);                           // NCOPY*64
    float*    bn1q   = bn1s + NCOPY * 64;                              // NCOPY*64
    float*    bn2s   = bn1q + NCOPY * 64;                              // NCOPY*64
    float*    bn2q   = bn2s + NCOPY * 64;                              // NCOPY*64
    float*    gsum   = bn2q + NCOPY * 64;                              // G*64
    float*    W2eff  = gsum + (size_t)G * 64;                          // 4096
    float*    c2     = W2eff + 4096;                                   // 64

    // --- zero accumulators ---
    hipMemsetAsync(indeg, 0, (size_t)N * 4, stream);
    hipMemsetAsync(bn1s, 0, (size_t)(4 * NCOPY * 64 + G * 64) * sizeof(float), stream);

    // --- fused degree count (int4) + GEMM1 ---
    k_deg_gemm1<<<2 * NGEMM1, 256, 0, stream>>>(x, W1, hd, ei, indeg);

    // --- CSR scan ---
    k_block_reduce<<<NB, 256, 0, stream>>>(indeg, bsum, N);
    k_scan_final<<<NB, 256, 0, stream>>>(indeg, bsum, rowptr, cursor, dinv, N);

    // --- XCD-partitioned fill ---
    k_fill<<<NFILL, 256, 0, stream>>>(ei, cursor, colidx);

    // --- layer 1 aggregate (neighbor-dinv scaled) + bias + relu + BN1 stats ---
    k_gather_fused<<<(N + 31) / 32, 256, 0, stream>>>(rowptr, colidx, hd, dinv, b1, act, bn1s, bn1q, N);
    k_bn_fold_w2<<<1, 64, 0, stream>>>(bn1s, bn1q, gamma1, beta1, W2, W2eff, c2, N);

    // --- layer 2: hd2 = (act@W2eff + c2)*dinv, fp16 ---
    k_gemm64_h<<<(N + 63) / 64, 256, 0, stream>>>(act, W2eff, c2, dinv, hd, N);
    k_gather_pool<<<(N + 31) / 32, 256, 0, stream>>>(rowptr, colidx, hd, dinv, b2, batch, gsum, bn2s, bn2q, N);

    // --- MLP (BN2 + pool finalize fused) ---
    k_mlp<<<G, 128, 0, stream>>>(gsum, batch, N, bn2s, bn2q, gamma2, beta2,
                                 fW1, fb1, fW2, fb2, fW3, fb3, fW4, fb4, oW, ob, out);
}